// Round 1
// baseline (2726.326 us; speedup 1.0000x reference)
//
#include <hip/hip_runtime.h>
#include <math.h>

#define TWO_PI 6.28318530717958647692f
#define NXD 64
#define NYD 64
#define NZD 40
#define CID 32
#define NJZ 16   // kept z bins: kz = 0..7, 13..20
#define NJY 32   // kept y bins (xy branch): ky = 0..15, 17..32

// ---------------- 1x1 conv: out[b,x,y,z,o] = sum_i X[...,i]*Wc[o,i] + bias[o]
__global__ __launch_bounds__(256) void k_conv(const float* __restrict__ X,
    const float* __restrict__ Wc, const float* __restrict__ bias,
    float* __restrict__ out) {
  __shared__ float W[32][33];
  __shared__ float bs[32];
  __shared__ float xr[8][32];
  int t = threadIdx.x;
  for (int k = t; k < 1024; k += 256) W[k >> 5][k & 31] = Wc[k];
  if (t < 32) bs[t] = bias[t];
  long base = (long)blockIdx.x * 256;  // 8 rows of 32 channels
  for (int k = t; k < 256; k += 256) xr[k >> 5][k & 31] = X[base + k];
  __syncthreads();
  int r = t >> 5, o = t & 31;
  float acc = bs[o];
  for (int i = 0; i < 32; ++i) acc += xr[r][i] * W[o][i];
  out[base + t] = acc;
}

// ---------------- z projection (shared by xz & yz branches)
// T[(x*64+y)*16 + j][i] = sum_z X[b,x,y,z,i] * e^{-2pi i kz_j z / 40}
__global__ __launch_bounds__(512) void k_zproj(const float* __restrict__ X,
    float2* __restrict__ T, int b) {
  __shared__ float xs[NZD][CID];
  __shared__ float2 tw[NJZ][NZD];
  int t = threadIdx.x;
  int xy = blockIdx.x;  // x*64 + y
  const float* src = X + ((long)(b * 4096 + xy)) * NZD * CID;
  for (int k = t; k < NZD * CID; k += 512) xs[k >> 5][k & 31] = src[k];
  for (int k = t; k < NJZ * NZD; k += 512) {
    int j = k / NZD, z = k % NZD;
    int kz = (j < 8) ? j : j + 5;
    int m = (kz * z) % NZD;
    float s_, c_; sincosf(TWO_PI * m / (float)NZD, &s_, &c_);
    tw[j][z] = make_float2(c_, -s_);
  }
  __syncthreads();
  int j = t >> 5, i = t & 31;
  float2 acc = make_float2(0.f, 0.f);
  for (int z = 0; z < NZD; ++z) {
    float v = xs[z][i];
    float2 w = tw[j][z];
    acc.x += v * w.x; acc.y += v * w.y;
  }
  T[((long)xy * NJZ + j) * CID + i] = acc;
}

// ---------------- fused forward-axis DFT (64 -> 16 modes) + channel mode-mix
// block (m, j). U[s][i] = sum_c T[c*strideC + s*strideS + j*32 + i] e^{-2pi i m c/64}
// V[(m*64+s)*16+j][o] = sum_i U[s][i]*W[i][o]   (W complex from fw/fw2, bins of 8)
__global__ __launch_bounds__(256) void k_fwdmix(const float2* __restrict__ T,
    float2* __restrict__ V, const float* __restrict__ fw, const float* __restrict__ fw2,
    int strideC, int strideS) {
  __shared__ float2 U[64][CID];
  __shared__ float2 Wm[CID][CID];
  __shared__ float2 twA[64];
  int m = blockIdx.x, j = blockIdx.y, t = threadIdx.x;
  if (t < 64) {
    int mm = (m * t) & 63;
    float s_, c_; sincosf(TWO_PI * mm / 64.0f, &s_, &c_);
    twA[t] = make_float2(c_, -s_);
  }
  {
    const float* src = (j < 8) ? fw : fw2;
    int jz = (j < 8) ? j : j - 8;
    for (int k = t; k < 1024; k += 256) {
      int i = k >> 5, o = k & 31;
      const float* p = src + ((((i * 32 + o) * 16 + m) * 8 + jz) * 2);
      Wm[i][o] = make_float2(p[0], p[1]);
    }
  }
  __syncthreads();
  int lane = t & 31, sg = t >> 5;
  for (int k = 0; k < 8; ++k) {
    int s = sg + 8 * k;
    float2 acc = make_float2(0.f, 0.f);
    const float2* p = T + (long)s * strideS + j * 32 + lane;
    for (int c = 0; c < 64; ++c) {
      float2 tv = p[(long)c * strideC];
      float2 w = twA[c];
      acc.x += tv.x * w.x - tv.y * w.y;
      acc.y += tv.x * w.y + tv.y * w.x;
    }
    U[s][lane] = acc;
  }
  __syncthreads();
  for (int k = 0; k < 8; ++k) {
    int s = sg + 8 * k;
    float2 acc = make_float2(0.f, 0.f);
    for (int i2 = 0; i2 < 32; ++i2) {
      float2 u = U[s][i2], w = Wm[i2][lane];
      acc.x += u.x * w.x - u.y * w.y;
      acc.y += u.x * w.y + u.y * w.x;
    }
    V[((long)(m * 64 + s) * NJZ + j) * CID + lane] = acc;
  }
}

// ---------------- inverse axis DFT (16 modes -> 64), unnormalized
// P[(v*64+s)*16+j][o] = sum_m V[(m*64+s)*16+j][o] e^{+2pi i m v/64}
__global__ __launch_bounds__(256) void k_invaxis(const float2* __restrict__ V,
    float2* __restrict__ P) {
  __shared__ float2 Vs[16][CID];
  __shared__ float2 twp[64];
  int s = blockIdx.x, j = blockIdx.y, t = threadIdx.x;
  if (t < 64) {
    float s_, c_; sincosf(TWO_PI * t / 64.0f, &s_, &c_);
    twp[t] = make_float2(c_, s_);
  }
  for (int k = t; k < 512; k += 256) {
    int mm = k >> 5, o = k & 31;
    Vs[mm][o] = V[((long)(mm * 64 + s) * NJZ + j) * CID + o];
  }
  __syncthreads();
  int o = t & 31, vg = t >> 5;
  for (int k = 0; k < 8; ++k) {
    int v = vg + 8 * k;
    float2 acc = make_float2(0.f, 0.f);
    for (int mm = 0; mm < 16; ++mm) {
      float2 w = twp[(mm * v) & 63];
      float2 vv = Vs[mm][o];
      acc.x += vv.x * w.x - vv.y * w.y;
      acc.y += vv.x * w.y + vv.y * w.x;
    }
    P[((long)(v * 64 + s) * NJZ + j) * CID + o] = acc;
  }
}

// ---------------- inverse real-z (16 bins -> 40) + accumulate into out
// out[b, v*strideV + s*strideS + z*32 + o] += (1/2560)*sum_j c_j Re{P * e^{+2pi i kz_j z/40}}
__global__ __launch_bounds__(256) void k_invzadd(const float2* __restrict__ P,
    float* __restrict__ out, long strideV, long strideS, int b) {
  __shared__ float2 czt[NJZ][NZD];
  int t = threadIdx.x;
  for (int k = t; k < NJZ * NZD; k += 256) {
    int j = k / NZD, z = k % NZD;
    int kz = (j < 8) ? j : j + 5;
    int mm = (kz * z) % NZD;
    float s_, c_; sincosf(TWO_PI * mm / (float)NZD, &s_, &c_);
    float cj = (kz == 0 || kz == 20) ? 1.0f : 2.0f;
    cj *= (1.0f / 2560.0f);
    czt[j][z] = make_float2(cj * c_, cj * s_);
  }
  __syncthreads();
  int v = blockIdx.x;
  int s = blockIdx.y * 8 + (t >> 5);
  int o = t & 31;
  float2 pr[16];
  const float2* pp = P + ((long)(v * 64 + s) * NJZ) * CID + o;
  for (int j = 0; j < 16; ++j) pr[j] = pp[(long)j * CID];
  float* op = out + (long)b * NXD * NYD * NZD * CID + v * strideV + s * strideS + o;
  for (int z = 0; z < NZD; ++z) {
    float acc = 0.f;
    float2 c;
    for (int j = 0; j < 16; ++j) {
      c = czt[j][z];
      acc += pr[j].x * c.x - pr[j].y * c.y;
    }
    op[(long)z * CID] += acc;
  }
}

// ---------------- xy branch: forward real-y DFT (64 -> 32 bins)
// S[(x*32+jy)*40 + z][i] = sum_y X[b,x,y,z,i] e^{-2pi i ky_jy y/64}
__global__ __launch_bounds__(256) void k_fwdy(const float* __restrict__ X,
    float2* __restrict__ S, int b) {
  __shared__ float xs[64][128];   // [y][zt*32+i], 4 z per chunk
  __shared__ float2 twy[NJY][64];
  int x = blockIdx.x, zc = blockIdx.y, t = threadIdx.x;
  int z0 = zc * 4;
  const float* base = X + (((long)b * 64 + x) * 64) * (long)NZD * CID;
  for (int k = t; k < 8192; k += 256) {
    int y = k >> 7, r = k & 127;
    int zt = r >> 5, i = r & 31;
    xs[y][r] = base[(long)y * (NZD * CID) + (z0 + zt) * CID + i];
  }
  for (int k = t; k < NJY * 64; k += 256) {
    int jy = k >> 6, y = k & 63;
    int ky = (jy < 16) ? jy : jy + 1;
    int mm = (ky * y) & 63;
    float s_, c_; sincosf(TWO_PI * mm / 64.0f, &s_, &c_);
    twy[jy][y] = make_float2(c_, -s_);
  }
  __syncthreads();
  int i = t & 31, g = t >> 5;
  for (int k2 = 0; k2 < 4; ++k2) {
    int jy = g * 4 + k2;
    for (int zt = 0; zt < 4; ++zt) {
      float2 acc = make_float2(0.f, 0.f);
      for (int y = 0; y < 64; ++y) {
        float v = xs[y][zt * 32 + i];
        float2 w = twy[jy][y];
        acc.x += v * w.x; acc.y += v * w.y;
      }
      S[(((long)x * NJY + jy) * NZD + z0 + zt) * CID + i] = acc;
    }
  }
}

// ---------------- xy branch: forward x DFT (64 -> 16) + mode mix
// block (kx, jy): U[z][i] = sum_x S[x-stride] e^{-2pi i kx x/64}; V2 = U * Wxy
__global__ __launch_bounds__(256) void k_fwdxmix_xy(const float2* __restrict__ S,
    float2* __restrict__ V2, const float* __restrict__ fw, const float* __restrict__ fw2) {
  __shared__ float2 U[NZD][CID];
  __shared__ float2 Wm[CID][CID];
  __shared__ float2 twA[64];
  int kx = blockIdx.x, jy = blockIdx.y, t = threadIdx.x;
  if (t < 64) {
    int mm = (kx * t) & 63;
    float s_, c_; sincosf(TWO_PI * mm / 64.0f, &s_, &c_);
    twA[t] = make_float2(c_, -s_);
  }
  const float* src = (jy < 16) ? fw : fw2;
  int kyl = (jy < 16) ? jy : jy - 16;
  for (int k = t; k < 1024; k += 256) {
    int i = k >> 5, o = k & 31;
    const float* p = src + (((i * 32 + o) * 16 + kx) * 16 + kyl) * 2;
    Wm[i][o] = make_float2(p[0], p[1]);
  }
  __syncthreads();
  int lane = t & 31, zg = t >> 5;
  for (int k = 0; k < 5; ++k) {
    int z = zg + 8 * k;
    float2 acc = make_float2(0.f, 0.f);
    const float2* p = S + ((long)jy * NZD + z) * CID + lane;
    for (int x = 0; x < 64; ++x) {
      float2 tv = p[(long)x * (NJY * NZD * CID)];
      float2 w = twA[x];
      acc.x += tv.x * w.x - tv.y * w.y;
      acc.y += tv.x * w.y + tv.y * w.x;
    }
    U[z][lane] = acc;
  }
  __syncthreads();
  for (int k = 0; k < 5; ++k) {
    int z = zg + 8 * k;
    float2 acc = make_float2(0.f, 0.f);
    for (int i2 = 0; i2 < 32; ++i2) {
      float2 u = U[z][i2], w = Wm[i2][lane];
      acc.x += u.x * w.x - u.y * w.y;
      acc.y += u.x * w.y + u.y * w.x;
    }
    V2[(((long)kx * NJY + jy) * NZD + z) * CID + lane] = acc;
  }
}

// ---------------- xy branch: inverse x DFT (16 -> 64), unnormalized
__global__ __launch_bounds__(256) void k_invx_xy(const float2* __restrict__ V2,
    float2* __restrict__ P2) {
  __shared__ float2 Vs[16][CID];
  __shared__ float2 twp[64];
  int jy = blockIdx.x, z = blockIdx.y, t = threadIdx.x;
  if (t < 64) {
    float s_, c_; sincosf(TWO_PI * t / 64.0f, &s_, &c_);
    twp[t] = make_float2(c_, s_);
  }
  for (int k = t; k < 512; k += 256) {
    int kx = k >> 5, o = k & 31;
    Vs[kx][o] = V2[(((long)kx * NJY + jy) * NZD + z) * CID + o];
  }
  __syncthreads();
  int o = t & 31, xg = t >> 5;
  for (int k = 0; k < 8; ++k) {
    int x = xg + 8 * k;
    float2 acc = make_float2(0.f, 0.f);
    for (int kx = 0; kx < 16; ++kx) {
      float2 w = twp[(kx * x) & 63];
      float2 v = Vs[kx][o];
      acc.x += v.x * w.x - v.y * w.y;
      acc.y += v.x * w.y + v.y * w.x;
    }
    P2[(((long)x * NJY + jy) * NZD + z) * CID + o] = acc;
  }
}

// ---------------- xy branch: inverse real-y (32 bins -> 64) + accumulate
__global__ __launch_bounds__(256) void k_invyadd(const float2* __restrict__ P2,
    float* __restrict__ out, int b) {
  __shared__ float2 cyt[NJY][64];
  int t = threadIdx.x;
  for (int k = t; k < NJY * 64; k += 256) {
    int jy = k >> 6, y = k & 63;
    int ky = (jy < 16) ? jy : jy + 1;
    int mm = (ky * y) & 63;
    float s_, c_; sincosf(TWO_PI * mm / 64.0f, &s_, &c_);
    float cj = (ky == 0 || ky == 32) ? 1.0f : 2.0f;
    cj *= (1.0f / 4096.0f);
    cyt[jy][y] = make_float2(cj * c_, cj * s_);
  }
  __syncthreads();
  int x = blockIdx.x;
  int y0 = blockIdx.y * 8;
  int o = t & 31, zg = t >> 5;
  float* ob = out + (long)b * NXD * NYD * NZD * CID + (long)x * NYD * NZD * CID;
  for (int k = 0; k < 5; ++k) {
    int z = zg + 8 * k;
    float2 pr[NJY];
    const float2* pp = P2 + (((long)x * NJY) * NZD + z) * CID + o;
    for (int jy = 0; jy < NJY; ++jy) pr[jy] = pp[(long)jy * (NZD * CID)];
    for (int yy = 0; yy < 8; ++yy) {
      int y = y0 + yy;
      float acc = 0.f;
      for (int jy = 0; jy < NJY; ++jy) {
        float2 c = cyt[jy][y];
        acc += pr[jy].x * c.x - pr[jy].y * c.y;
      }
      ob[((long)y * NZD + z) * CID + o] += acc;
    }
  }
}

// ---------------- in-place FFN: out = relu(out@W0^T + b0)@W1^T + b1
__global__ __launch_bounds__(256) void k_ff(float* __restrict__ out,
    const float* __restrict__ W0, const float* __restrict__ b0,
    const float* __restrict__ W1, const float* __restrict__ b1) {
  __shared__ float w0[64][33];
  __shared__ float w1[32][65];
  __shared__ float hb[8][32];
  __shared__ float h1[8][64];
  __shared__ float b0s[64], b1s[32];
  int t = threadIdx.x;
  for (int k = t; k < 2048; k += 256) w0[k >> 5][k & 31] = W0[k];
  for (int k = t; k < 2048; k += 256) w1[k >> 6][k & 63] = W1[k];
  if (t < 64) b0s[t] = b0[t];
  if (t < 32) b1s[t] = b1[t];
  long base = (long)blockIdx.x * 256;
  for (int k = t; k < 256; k += 256) hb[k >> 5][k & 31] = out[base + k];
  __syncthreads();
  int r = t >> 5, o = t & 31;
  for (int m = 0; m < 2; ++m) {
    int hh = o + 32 * m;
    float a = b0s[hh];
    for (int i = 0; i < 32; ++i) a += hb[r][i] * w0[hh][i];
    h1[r][hh] = a > 0.f ? a : 0.f;
  }
  __syncthreads();
  float a = b1s[o];
  for (int i = 0; i < 64; ++i) a += h1[r][i] * w1[o][i];
  out[base + t] = a;
}

extern "C" void kernel_launch(void* const* d_in, const int* in_sizes, int n_in,
                              void* d_out, int out_size, void* d_ws, size_t ws_size,
                              hipStream_t stream) {
  const float* X       = (const float*)d_in[0];
  const float* w_w     = (const float*)d_in[1];
  const float* w_b     = (const float*)d_in[2];
  const float* fw_xy   = (const float*)d_in[3];
  const float* fw_yz   = (const float*)d_in[4];
  const float* fw_xz   = (const float*)d_in[5];
  const float* fw2_xy  = (const float*)d_in[6];
  const float* fw2_yz  = (const float*)d_in[7];
  const float* fw2_xz  = (const float*)d_in[8];
  const float* ff_w0   = (const float*)d_in[9];
  const float* ff_b0   = (const float*)d_in[10];
  const float* ff_w1   = (const float*)d_in[11];
  const float* ff_b1   = (const float*)d_in[12];
  float* out = (float*)d_out;

  char* ws = (char*)d_ws;
  // region1: max(T 2097152, S 2621440) float2; region2: max(V 524288, V2 655360);
  // region3: max(P 2097152, P2 2621440). Total = 47,185,920 bytes.
  float2* r1 = (float2*)ws;
  float2* r2 = (float2*)(ws + 2621440ll * 8);
  float2* r3 = (float2*)(ws + (2621440ll + 655360ll) * 8);

  k_conv<<<dim3(81920), dim3(256), 0, stream>>>(X, w_w, w_b, out);

  for (int b = 0; b < 4; ++b) {
    // shared z-projection for xz & yz
    k_zproj<<<dim3(4096), dim3(512), 0, stream>>>(X, r1, b);
    // xz branch: contract x (strideC=64*16*32), spectator y (strideS=16*32)
    k_fwdmix<<<dim3(16, 16), dim3(256), 0, stream>>>(r1, r2, fw_xz, fw2_xz, 32768, 512);
    k_invaxis<<<dim3(64, 16), dim3(256), 0, stream>>>(r2, r3);
    k_invzadd<<<dim3(64, 8), dim3(256), 0, stream>>>(r3, out, 64 * 40 * 32, 40 * 32, b);
    // yz branch: contract y, spectator x
    k_fwdmix<<<dim3(16, 16), dim3(256), 0, stream>>>(r1, r2, fw_yz, fw2_yz, 512, 32768);
    k_invaxis<<<dim3(64, 16), dim3(256), 0, stream>>>(r2, r3);
    k_invzadd<<<dim3(64, 8), dim3(256), 0, stream>>>(r3, out, 40 * 32, 64 * 40 * 32, b);
    // xy branch
    k_fwdy<<<dim3(64, 10), dim3(256), 0, stream>>>(X, r1, b);
    k_fwdxmix_xy<<<dim3(16, 32), dim3(256), 0, stream>>>(r1, r2, fw_xy, fw2_xy);
    k_invx_xy<<<dim3(32, 40), dim3(256), 0, stream>>>(r2, r3);
    k_invyadd<<<dim3(64, 8), dim3(256), 0, stream>>>(r3, out, b);
  }

  k_ff<<<dim3(81920), dim3(256), 0, stream>>>(out, ff_w0, ff_b0, ff_w1, ff_b1);
}

// Round 2
// 2031.648 us; speedup vs baseline: 1.3419x; 1.3419x over previous
//
#include <hip/hip_runtime.h>
#include <math.h>

#define TWO_PI 6.28318530717958647692f
#define NXD 64
#define NYD 64
#define NZD 40
#define CID 32
#define NJZ 16   // kept z bins: kz = 0..7, 13..20
#define NJY 32   // kept y bins (xy branch): ky = 0..15, 17..32

// workspace slot strides (float2 elements per batch-slot)
#define R1SLOT 2621440ll   // max(T=2097152, S=2621440)
#define R2SLOT 655360ll    // max(V=524288, V2=655360)
#define R3SLOT 2621440ll   // max(P=2097152, P2=2621440)

typedef __attribute__((ext_vector_type(8))) short short8;
typedef __attribute__((ext_vector_type(4))) float float4v;

__device__ inline unsigned short f2bf(float f) {
  unsigned u = __builtin_bit_cast(unsigned, f);
  unsigned r = (u + 0x7fffu + ((u >> 16) & 1u)) >> 16;
  return (unsigned short)r;
}

// ---------------- 1x1 conv via MFMA: out[m, o] = sum_i X[m, i]*Wc[o, i] + bias[o]
// rows m = b*x*y*z flattened (655360), K=32, N=32
__global__ __launch_bounds__(256) void k_conv_mfma(const float* __restrict__ X,
    const float* __restrict__ Wc, const float* __restrict__ bias,
    float* __restrict__ out) {
  int t = threadIdx.x;
  int wid = t >> 6, lane = t & 63;
  int l15 = lane & 15, quad = lane >> 4;
  // B frags: B[k=i][n=o] = Wc[o*32+i]; lane holds n=nt*16+l15, k=quad*8+j
  short8 B[2];
  float bb[2];
  for (int nt = 0; nt < 2; ++nt) {
    int o = nt * 16 + l15;
    for (int j = 0; j < 8; ++j) B[nt][j] = (short)f2bf(Wc[o * 32 + quad * 8 + j]);
    bb[nt] = bias[o];
  }
  const int TOT = 40960;  // 655360 rows / 16
  int wg = blockIdx.x * 4 + wid;
  for (int tt = wg; tt < TOT; tt += gridDim.x * 4) {
    long r0 = (long)tt * 16;
    const float4v* p = (const float4v*)(X + (r0 + l15) * 32 + quad * 8);
    float4v x0 = p[0], x1 = p[1];
    short8 a;
    for (int j = 0; j < 4; ++j) { a[j] = (short)f2bf(x0[j]); a[4 + j] = (short)f2bf(x1[j]); }
    for (int nt = 0; nt < 2; ++nt) {
      float4v acc = {0.f, 0.f, 0.f, 0.f};
      acc = __builtin_amdgcn_mfma_f32_16x16x32_bf16(a, B[nt], acc, 0, 0, 0);
      for (int r = 0; r < 4; ++r)
        out[(r0 + quad * 4 + r) * 32 + nt * 16 + l15] = acc[r] + bb[nt];
    }
  }
}

// ---------------- z projection (shared by xz & yz branches)
__global__ __launch_bounds__(512) void k_zproj(const float* __restrict__ X,
    float2* __restrict__ Tb, int b0) {
  __shared__ float xs[NZD][CID];
  __shared__ float2 tw[NJZ][NZD];
  int t = threadIdx.x;
  int xy = blockIdx.x;  // x*64 + y
  int b = b0 + blockIdx.z;
  float2* T = Tb + (long)blockIdx.z * R1SLOT;
  const float* src = X + ((long)(b * 4096 + xy)) * NZD * CID;
  for (int k = t; k < NZD * CID; k += 512) xs[k >> 5][k & 31] = src[k];
  for (int k = t; k < NJZ * NZD; k += 512) {
    int j = k / NZD, z = k % NZD;
    int kz = (j < 8) ? j : j + 5;
    int m = (kz * z) % NZD;
    float s_, c_; sincosf(TWO_PI * m / (float)NZD, &s_, &c_);
    tw[j][z] = make_float2(c_, -s_);
  }
  __syncthreads();
  int j = t >> 5, i = t & 31;
  float2 acc = make_float2(0.f, 0.f);
  for (int z = 0; z < NZD; ++z) {
    float v = xs[z][i];
    float2 w = tw[j][z];
    acc.x += v * w.x; acc.y += v * w.y;
  }
  T[((long)xy * NJZ + j) * CID + i] = acc;
}

// ---------------- fused forward-axis DFT (64 -> 16 modes) + channel mode-mix
__global__ __launch_bounds__(256) void k_fwdmix(const float2* __restrict__ Tb,
    float2* __restrict__ Vb, const float* __restrict__ fw, const float* __restrict__ fw2,
    int strideC, int strideS) {
  __shared__ float2 U[64][CID];
  __shared__ float2 Wm[CID][CID];
  __shared__ float2 twA[64];
  int m = blockIdx.x, j = blockIdx.y, t = threadIdx.x;
  const float2* T = Tb + (long)blockIdx.z * R1SLOT;
  float2* V = Vb + (long)blockIdx.z * R2SLOT;
  if (t < 64) {
    int mm = (m * t) & 63;
    float s_, c_; sincosf(TWO_PI * mm / 64.0f, &s_, &c_);
    twA[t] = make_float2(c_, -s_);
  }
  {
    const float* src = (j < 8) ? fw : fw2;
    int jz = (j < 8) ? j : j - 8;
    for (int k = t; k < 1024; k += 256) {
      int i = k >> 5, o = k & 31;
      const float* p = src + ((((i * 32 + o) * 16 + m) * 8 + jz) * 2);
      Wm[i][o] = make_float2(p[0], p[1]);
    }
  }
  __syncthreads();
  int lane = t & 31, sg = t >> 5;
  for (int k = 0; k < 8; ++k) {
    int s = sg + 8 * k;
    float2 acc = make_float2(0.f, 0.f);
    const float2* p = T + (long)s * strideS + j * 32 + lane;
    for (int c = 0; c < 64; ++c) {
      float2 tv = p[(long)c * strideC];
      float2 w = twA[c];
      acc.x += tv.x * w.x - tv.y * w.y;
      acc.y += tv.x * w.y + tv.y * w.x;
    }
    U[s][lane] = acc;
  }
  __syncthreads();
  for (int k = 0; k < 8; ++k) {
    int s = sg + 8 * k;
    float2 acc = make_float2(0.f, 0.f);
    for (int i2 = 0; i2 < 32; ++i2) {
      float2 u = U[s][i2], w = Wm[i2][lane];
      acc.x += u.x * w.x - u.y * w.y;
      acc.y += u.x * w.y + u.y * w.x;
    }
    V[((long)(m * 64 + s) * NJZ + j) * CID + lane] = acc;
  }
}

// ---------------- inverse axis DFT (16 modes -> 64), unnormalized
__global__ __launch_bounds__(256) void k_invaxis(const float2* __restrict__ Vb,
    float2* __restrict__ Pb) {
  __shared__ float2 Vs[16][CID];
  __shared__ float2 twp[64];
  int s = blockIdx.x, j = blockIdx.y, t = threadIdx.x;
  const float2* V = Vb + (long)blockIdx.z * R2SLOT;
  float2* P = Pb + (long)blockIdx.z * R3SLOT;
  if (t < 64) {
    float s_, c_; sincosf(TWO_PI * t / 64.0f, &s_, &c_);
    twp[t] = make_float2(c_, s_);
  }
  for (int k = t; k < 512; k += 256) {
    int mm = k >> 5, o = k & 31;
    Vs[mm][o] = V[((long)(mm * 64 + s) * NJZ + j) * CID + o];
  }
  __syncthreads();
  int o = t & 31, vg = t >> 5;
  for (int k = 0; k < 8; ++k) {
    int v = vg + 8 * k;
    float2 acc = make_float2(0.f, 0.f);
    for (int mm = 0; mm < 16; ++mm) {
      float2 w = twp[(mm * v) & 63];
      float2 vv = Vs[mm][o];
      acc.x += vv.x * w.x - vv.y * w.y;
      acc.y += vv.x * w.y + vv.y * w.x;
    }
    P[((long)(v * 64 + s) * NJZ + j) * CID + o] = acc;
  }
}

// ---------------- inverse real-z (16 bins -> 40) + accumulate into out
__global__ __launch_bounds__(256) void k_invzadd(const float2* __restrict__ Pb,
    float* __restrict__ out, long strideV, long strideS, int b0) {
  __shared__ float2 czt[NJZ][NZD];
  int t = threadIdx.x;
  int b = b0 + blockIdx.z;
  const float2* P = Pb + (long)blockIdx.z * R3SLOT;
  for (int k = t; k < NJZ * NZD; k += 256) {
    int j = k / NZD, z = k % NZD;
    int kz = (j < 8) ? j : j + 5;
    int mm = (kz * z) % NZD;
    float s_, c_; sincosf(TWO_PI * mm / (float)NZD, &s_, &c_);
    float cj = (kz == 0 || kz == 20) ? 1.0f : 2.0f;
    cj *= (1.0f / 2560.0f);
    czt[j][z] = make_float2(cj * c_, cj * s_);
  }
  __syncthreads();
  int v = blockIdx.x;
  int s = blockIdx.y * 8 + (t >> 5);
  int o = t & 31;
  float2 pr[16];
  const float2* pp = P + ((long)(v * 64 + s) * NJZ) * CID + o;
  for (int j = 0; j < 16; ++j) pr[j] = pp[(long)j * CID];
  float* op = out + (long)b * NXD * NYD * NZD * CID + v * strideV + s * strideS + o;
  for (int z = 0; z < NZD; ++z) {
    float acc = 0.f;
    for (int j = 0; j < 16; ++j) {
      float2 c = czt[j][z];
      acc += pr[j].x * c.x - pr[j].y * c.y;
    }
    op[(long)z * CID] += acc;
  }
}

// ---------------- xy branch: forward real-y DFT (64 -> 32 bins)
__global__ __launch_bounds__(256) void k_fwdy(const float* __restrict__ X,
    float2* __restrict__ Sb, int b0) {
  __shared__ float xs[64][128];   // [y][zt*32+i], 4 z per chunk
  __shared__ float2 twy[NJY][64];
  int x = blockIdx.x, zc = blockIdx.y, t = threadIdx.x;
  int b = b0 + blockIdx.z;
  float2* S = Sb + (long)blockIdx.z * R1SLOT;
  int z0 = zc * 4;
  const float* base = X + (((long)b * 64 + x) * 64) * (long)NZD * CID;
  for (int k = t; k < 8192; k += 256) {
    int y = k >> 7, r = k & 127;
    int zt = r >> 5, i = r & 31;
    xs[y][r] = base[(long)y * (NZD * CID) + (z0 + zt) * CID + i];
  }
  for (int k = t; k < NJY * 64; k += 256) {
    int jy = k >> 6, y = k & 63;
    int ky = (jy < 16) ? jy : jy + 1;
    int mm = (ky * y) & 63;
    float s_, c_; sincosf(TWO_PI * mm / 64.0f, &s_, &c_);
    twy[jy][y] = make_float2(c_, -s_);
  }
  __syncthreads();
  int i = t & 31, g = t >> 5;
  for (int k2 = 0; k2 < 4; ++k2) {
    int jy = g * 4 + k2;
    for (int zt = 0; zt < 4; ++zt) {
      float2 acc = make_float2(0.f, 0.f);
      for (int y = 0; y < 64; ++y) {
        float v = xs[y][zt * 32 + i];
        float2 w = twy[jy][y];
        acc.x += v * w.x; acc.y += v * w.y;
      }
      S[(((long)x * NJY + jy) * NZD + z0 + zt) * CID + i] = acc;
    }
  }
}

// ---------------- xy branch: forward x DFT (64 -> 16) + mode mix
__global__ __launch_bounds__(256) void k_fwdxmix_xy(const float2* __restrict__ Sb,
    float2* __restrict__ V2b, const float* __restrict__ fw, const float* __restrict__ fw2) {
  __shared__ float2 U[NZD][CID];
  __shared__ float2 Wm[CID][CID];
  __shared__ float2 twA[64];
  int kx = blockIdx.x, jy = blockIdx.y, t = threadIdx.x;
  const float2* S = Sb + (long)blockIdx.z * R1SLOT;
  float2* V2 = V2b + (long)blockIdx.z * R2SLOT;
  if (t < 64) {
    int mm = (kx * t) & 63;
    float s_, c_; sincosf(TWO_PI * mm / 64.0f, &s_, &c_);
    twA[t] = make_float2(c_, -s_);
  }
  const float* src = (jy < 16) ? fw : fw2;
  int kyl = (jy < 16) ? jy : jy - 16;
  for (int k = t; k < 1024; k += 256) {
    int i = k >> 5, o = k & 31;
    const float* p = src + (((i * 32 + o) * 16 + kx) * 16 + kyl) * 2;
    Wm[i][o] = make_float2(p[0], p[1]);
  }
  __syncthreads();
  int lane = t & 31, zg = t >> 5;
  for (int k = 0; k < 5; ++k) {
    int z = zg + 8 * k;
    float2 acc = make_float2(0.f, 0.f);
    const float2* p = S + ((long)jy * NZD + z) * CID + lane;
    for (int x = 0; x < 64; ++x) {
      float2 tv = p[(long)x * (NJY * NZD * CID)];
      float2 w = twA[x];
      acc.x += tv.x * w.x - tv.y * w.y;
      acc.y += tv.x * w.y + tv.y * w.x;
    }
    U[z][lane] = acc;
  }
  __syncthreads();
  for (int k = 0; k < 5; ++k) {
    int z = zg + 8 * k;
    float2 acc = make_float2(0.f, 0.f);
    for (int i2 = 0; i2 < 32; ++i2) {
      float2 u = U[z][i2], w = Wm[i2][lane];
      acc.x += u.x * w.x - u.y * w.y;
      acc.y += u.x * w.y + u.y * w.x;
    }
    V2[(((long)kx * NJY + jy) * NZD + z) * CID + lane] = acc;
  }
}

// ---------------- xy branch: inverse x DFT (16 -> 64), unnormalized
__global__ __launch_bounds__(256) void k_invx_xy(const float2* __restrict__ V2b,
    float2* __restrict__ P2b) {
  __shared__ float2 Vs[16][CID];
  __shared__ float2 twp[64];
  int jy = blockIdx.x, z = blockIdx.y, t = threadIdx.x;
  const float2* V2 = V2b + (long)blockIdx.z * R2SLOT;
  float2* P2 = P2b + (long)blockIdx.z * R3SLOT;
  if (t < 64) {
    float s_, c_; sincosf(TWO_PI * t / 64.0f, &s_, &c_);
    twp[t] = make_float2(c_, s_);
  }
  for (int k = t; k < 512; k += 256) {
    int kx = k >> 5, o = k & 31;
    Vs[kx][o] = V2[(((long)kx * NJY + jy) * NZD + z) * CID + o];
  }
  __syncthreads();
  int o = t & 31, xg = t >> 5;
  for (int k = 0; k < 8; ++k) {
    int x = xg + 8 * k;
    float2 acc = make_float2(0.f, 0.f);
    for (int kx = 0; kx < 16; ++kx) {
      float2 w = twp[(kx * x) & 63];
      float2 v = Vs[kx][o];
      acc.x += v.x * w.x - v.y * w.y;
      acc.y += v.x * w.y + v.y * w.x;
    }
    P2[(((long)x * NJY + jy) * NZD + z) * CID + o] = acc;
  }
}

// ---------------- xy branch: inverse real-y (32 bins -> 64) + accumulate
__global__ __launch_bounds__(256) void k_invyadd(const float2* __restrict__ P2b,
    float* __restrict__ out, int b0) {
  __shared__ float2 cyt[NJY][64];
  int t = threadIdx.x;
  int b = b0 + blockIdx.z;
  const float2* P2 = P2b + (long)blockIdx.z * R3SLOT;
  for (int k = t; k < NJY * 64; k += 256) {
    int jy = k >> 6, y = k & 63;
    int ky = (jy < 16) ? jy : jy + 1;
    int mm = (ky * y) & 63;
    float s_, c_; sincosf(TWO_PI * mm / 64.0f, &s_, &c_);
    float cj = (ky == 0 || ky == 32) ? 1.0f : 2.0f;
    cj *= (1.0f / 4096.0f);
    cyt[jy][y] = make_float2(cj * c_, cj * s_);
  }
  __syncthreads();
  int x = blockIdx.x;
  int y0 = blockIdx.y * 8;
  int o = t & 31, zg = t >> 5;
  float* ob = out + (long)b * NXD * NYD * NZD * CID + (long)x * NYD * NZD * CID;
  for (int k = 0; k < 5; ++k) {
    int z = zg + 8 * k;
    float2 pr[NJY];
    const float2* pp = P2 + (((long)x * NJY) * NZD + z) * CID + o;
    for (int jy = 0; jy < NJY; ++jy) pr[jy] = pp[(long)jy * (NZD * CID)];
    for (int yy = 0; yy < 8; ++yy) {
      int y = y0 + yy;
      float acc = 0.f;
      for (int jy = 0; jy < NJY; ++jy) {
        float2 c = cyt[jy][y];
        acc += pr[jy].x * c.x - pr[jy].y * c.y;
      }
      ob[((long)y * NZD + z) * CID + o] += acc;
    }
  }
}

// ---------------- FFN via MFMA, in-place on out.
// GEMM1: h1[m, hh] = relu(sum_i h[m,i] W0[hh,i] + b0[hh])  (K=32, N=64)
// GEMM2: out[m, o] = sum_hh h1[m,hh] W1[o,hh] + b1[o]       (K=64, N=32)
__global__ __launch_bounds__(256) void k_ff_mfma(float* __restrict__ out,
    const float* __restrict__ W0, const float* __restrict__ b0,
    const float* __restrict__ W1, const float* __restrict__ b1) {
  __shared__ unsigned short h1s[4][16 * 64];  // per-wave bf16 tile
  int t = threadIdx.x;
  int wid = t >> 6, lane = t & 63;
  int l15 = lane & 15, quad = lane >> 4;
  short8 B1[4];
  float bb0[4];
  for (int nt = 0; nt < 4; ++nt) {
    int hh = nt * 16 + l15;
    for (int j = 0; j < 8; ++j) B1[nt][j] = (short)f2bf(W0[hh * 32 + quad * 8 + j]);
    bb0[nt] = b0[hh];
  }
  short8 B2[2][2];
  float bb1[2];
  for (int k0 = 0; k0 < 2; ++k0)
    for (int nt = 0; nt < 2; ++nt) {
      int o = nt * 16 + l15;
      for (int j = 0; j < 8; ++j)
        B2[k0][nt][j] = (short)f2bf(W1[o * 64 + k0 * 32 + quad * 8 + j]);
    }
  for (int nt = 0; nt < 2; ++nt) bb1[nt] = b1[nt * 16 + l15];

  const int TOT = 40960;  // 655360 rows / 16
  int wg = blockIdx.x * 4 + wid;
  unsigned short* hs = h1s[wid];
  for (int tt = wg; tt < TOT; tt += gridDim.x * 4) {
    long r0 = (long)tt * 16;
    const float4v* p = (const float4v*)(out + (r0 + l15) * 32 + quad * 8);
    float4v x0 = p[0], x1 = p[1];
    short8 a1;
    for (int j = 0; j < 4; ++j) { a1[j] = (short)f2bf(x0[j]); a1[4 + j] = (short)f2bf(x1[j]); }
    for (int nt = 0; nt < 4; ++nt) {
      float4v acc = {0.f, 0.f, 0.f, 0.f};
      acc = __builtin_amdgcn_mfma_f32_16x16x32_bf16(a1, B1[nt], acc, 0, 0, 0);
      for (int r = 0; r < 4; ++r) {
        float v = acc[r] + bb0[nt];
        v = v > 0.f ? v : 0.f;
        hs[(quad * 4 + r) * 64 + nt * 16 + l15] = f2bf(v);
      }
    }
    short8 a2[2];
    for (int k0 = 0; k0 < 2; ++k0)
      a2[k0] = *(const short8*)&hs[l15 * 64 + k0 * 32 + quad * 8];
    for (int nt = 0; nt < 2; ++nt) {
      float4v acc = {0.f, 0.f, 0.f, 0.f};
      acc = __builtin_amdgcn_mfma_f32_16x16x32_bf16(a2[0], B2[0][nt], acc, 0, 0, 0);
      acc = __builtin_amdgcn_mfma_f32_16x16x32_bf16(a2[1], B2[1][nt], acc, 0, 0, 0);
      for (int r = 0; r < 4; ++r)
        out[(r0 + quad * 4 + r) * 32 + nt * 16 + l15] = acc[r] + bb1[nt];
    }
  }
}

extern "C" void kernel_launch(void* const* d_in, const int* in_sizes, int n_in,
                              void* d_out, int out_size, void* d_ws, size_t ws_size,
                              hipStream_t stream) {
  const float* X       = (const float*)d_in[0];
  const float* w_w     = (const float*)d_in[1];
  const float* w_b     = (const float*)d_in[2];
  const float* fw_xy   = (const float*)d_in[3];
  const float* fw_yz   = (const float*)d_in[4];
  const float* fw_xz   = (const float*)d_in[5];
  const float* fw2_xy  = (const float*)d_in[6];
  const float* fw2_yz  = (const float*)d_in[7];
  const float* fw2_xz  = (const float*)d_in[8];
  const float* ff_w0   = (const float*)d_in[9];
  const float* ff_b0   = (const float*)d_in[10];
  const float* ff_w1   = (const float*)d_in[11];
  const float* ff_b1   = (const float*)d_in[12];
  float* out = (float*)d_out;
  char* ws = (char*)d_ws;

  // full-batch mode needs 4 slots in each region: (R1+R2+R3)*4*8 bytes
  const size_t need_full = (size_t)(R1SLOT + R2SLOT + R3SLOT) * 4 * 8;
  bool full = ws_size >= need_full;

  float2 *r1, *r2, *r3;
  if (full) {
    r1 = (float2*)ws;
    r2 = (float2*)(ws + (size_t)R1SLOT * 4 * 8);
    r3 = (float2*)(ws + (size_t)(R1SLOT + R2SLOT) * 4 * 8);
  } else {
    r1 = (float2*)ws;
    r2 = (float2*)(ws + (size_t)R1SLOT * 8);
    r3 = (float2*)(ws + (size_t)(R1SLOT + R2SLOT) * 8);
  }

  k_conv_mfma<<<dim3(2560), dim3(256), 0, stream>>>(X, w_w, w_b, out);

  int nz = full ? 4 : 1;
  int nb = full ? 1 : 4;
  for (int b = 0; b < nb; ++b) {
    // shared z-projection for xz & yz
    k_zproj<<<dim3(4096, 1, nz), dim3(512), 0, stream>>>(X, r1, b);
    // xz branch: contract x (strideC=64*16*32), spectator y (strideS=16*32)
    k_fwdmix<<<dim3(16, 16, nz), dim3(256), 0, stream>>>(r1, r2, fw_xz, fw2_xz, 32768, 512);
    k_invaxis<<<dim3(64, 16, nz), dim3(256), 0, stream>>>(r2, r3);
    k_invzadd<<<dim3(64, 8, nz), dim3(256), 0, stream>>>(r3, out, 64 * 40 * 32, 40 * 32, b);
    // yz branch: contract y, spectator x
    k_fwdmix<<<dim3(16, 16, nz), dim3(256), 0, stream>>>(r1, r2, fw_yz, fw2_yz, 512, 32768);
    k_invaxis<<<dim3(64, 16, nz), dim3(256), 0, stream>>>(r2, r3);
    k_invzadd<<<dim3(64, 8, nz), dim3(256), 0, stream>>>(r3, out, 40 * 32, 64 * 40 * 32, b);
    // xy branch
    k_fwdy<<<dim3(64, 10, nz), dim3(256), 0, stream>>>(X, r1, b);
    k_fwdxmix_xy<<<dim3(16, 32, nz), dim3(256), 0, stream>>>(r1, r2, fw_xy, fw2_xy);
    k_invx_xy<<<dim3(32, 40, nz), dim3(256), 0, stream>>>(r2, r3);
    k_invyadd<<<dim3(64, 8, nz), dim3(256), 0, stream>>>(r3, out, b);
  }

  k_ff_mfma<<<dim3(2560), dim3(256), 0, stream>>>(out, ff_w0, ff_b0, ff_w1, ff_b1);
}

// Round 3
// 1290.813 us; speedup vs baseline: 2.1121x; 1.5739x over previous
//
#include <hip/hip_runtime.h>
#include <math.h>

#define TWO_PI 6.28318530717958647692f
#define NXD 64
#define NYD 64
#define NZD 40
#define CID 32
#define NJZ 16   // kept z bins: kz = 0..7, 13..20
#define NJY 32   // kept y bins (xy branch): ky = 0..15, 17..32

// workspace slot strides (float2 elements per batch-slot)
#define R1SLOT 2621440ll   // max(T=2097152, S=2621440)
#define R2SLOT 655360ll    // max(V=524288, V2=655360)
#define R3SLOT 2621440ll   // max(P=2097152, P2=2621440, U=655360)

typedef __attribute__((ext_vector_type(8))) short short8;
typedef __attribute__((ext_vector_type(4))) float float4v;

__device__ inline unsigned short f2bf(float f) {
  unsigned u = __builtin_bit_cast(unsigned, f);
  unsigned r = (u + 0x7fffu + ((u >> 16) & 1u)) >> 16;
  return (unsigned short)r;
}

// ---------------- 1x1 conv via MFMA
__global__ __launch_bounds__(256) void k_conv_mfma(const float* __restrict__ X,
    const float* __restrict__ Wc, const float* __restrict__ bias,
    float* __restrict__ out) {
  int t = threadIdx.x;
  int wid = t >> 6, lane = t & 63;
  int l15 = lane & 15, quad = lane >> 4;
  short8 B[2];
  float bb[2];
  for (int nt = 0; nt < 2; ++nt) {
    int o = nt * 16 + l15;
    for (int j = 0; j < 8; ++j) B[nt][j] = (short)f2bf(Wc[o * 32 + quad * 8 + j]);
    bb[nt] = bias[o];
  }
  const int TOT = 40960;
  int wg = blockIdx.x * 4 + wid;
  for (int tt = wg; tt < TOT; tt += gridDim.x * 4) {
    long r0 = (long)tt * 16;
    const float4v* p = (const float4v*)(X + (r0 + l15) * 32 + quad * 8);
    float4v x0 = p[0], x1 = p[1];
    short8 a;
    for (int j = 0; j < 4; ++j) { a[j] = (short)f2bf(x0[j]); a[4 + j] = (short)f2bf(x1[j]); }
    for (int nt = 0; nt < 2; ++nt) {
      float4v acc = {0.f, 0.f, 0.f, 0.f};
      acc = __builtin_amdgcn_mfma_f32_16x16x32_bf16(a, B[nt], acc, 0, 0, 0);
      for (int r = 0; r < 4; ++r)
        out[(r0 + quad * 4 + r) * 32 + nt * 16 + l15] = acc[r] + bb[nt];
    }
  }
}

// ---------------- z projection (shared by xz & yz branches)
__global__ __launch_bounds__(512) void k_zproj(const float* __restrict__ X,
    float2* __restrict__ Tb, int b0) {
  __shared__ float xs[NZD][CID];
  __shared__ float2 tw[NJZ][NZD];
  int t = threadIdx.x;
  int xy = blockIdx.x;
  int b = b0 + blockIdx.z;
  float2* T = Tb + (long)blockIdx.z * R1SLOT;
  const float* src = X + ((long)(b * 4096 + xy)) * NZD * CID;
  for (int k = t; k < NZD * CID; k += 512) xs[k >> 5][k & 31] = src[k];
  for (int k = t; k < NJZ * NZD; k += 512) {
    int j = k / NZD, z = k % NZD;
    int kz = (j < 8) ? j : j + 5;
    int m = (kz * z) % NZD;
    float s_, c_; sincosf(TWO_PI * m / (float)NZD, &s_, &c_);
    tw[j][z] = make_float2(c_, -s_);
  }
  __syncthreads();
  int j = t >> 5, i = t & 31;
  float2 acc = make_float2(0.f, 0.f);
  for (int z = 0; z < NZD; ++z) {
    float v = xs[z][i];
    float2 w = tw[j][z];
    acc.x += v * w.x; acc.y += v * w.y;
  }
  T[((long)xy * NJZ + j) * CID + i] = acc;
}

// ---------------- streaming forward-axis DFT (64 -> 16 modes), amplification-free.
// grid (J, SD/8, nz). Block (j, s-chunk): thread owns (s,i), keeps 16 mode-accums
// in registers, reads each input element exactly once (coalesced 2KB bursts).
// in element index: c*CS + s*SS + j*JS + i. out: U[((m*J+j)*SD+s)*32+i].
__global__ __launch_bounds__(256) void k_fwddft(const float2* __restrict__ inb,
    float2* __restrict__ Ub, long CS, long SS, long JS) {
  __shared__ float2 tw[64];
  int t = threadIdx.x;
  if (t < 64) {
    float s_, c_; sincosf(TWO_PI * t / 64.0f, &s_, &c_);
    tw[t] = make_float2(c_, -s_);
  }
  int j = blockIdx.x, sc = blockIdx.y;
  int J = gridDim.x, SD = gridDim.y * 8;
  int s = sc * 8 + (t >> 5), i = t & 31;
  const float2* in = inb + (long)blockIdx.z * R1SLOT + (long)j * JS + (long)s * SS + i;
  float2 acc[16];
#pragma unroll
  for (int m = 0; m < 16; ++m) acc[m] = make_float2(0.f, 0.f);
  __syncthreads();
  for (int c = 0; c < 64; ++c) {
    float2 v = in[(long)c * CS];
#pragma unroll
    for (int m = 0; m < 16; ++m) {
      float2 w = tw[(m * c) & 63];
      acc[m].x += v.x * w.x - v.y * w.y;
      acc[m].y += v.x * w.y + v.y * w.x;
    }
  }
  float2* U = Ub + (long)blockIdx.z * R3SLOT;
#pragma unroll
  for (int m = 0; m < 16; ++m)
    U[((long)(m * J + j) * SD + s) * 32 + i] = acc[m];
}

// ---------------- unified channel mode-mix: V[m,j,s,o] = sum_i U[m,j,s,i]*W[m,j][i][o]
// grid (16, J, nz). W complex from fw (j<jsplit) else fw2, inner dim JW.
__global__ __launch_bounds__(256) void k_mix(const float2* __restrict__ Ub,
    float2* __restrict__ Vb, const float* __restrict__ fw, const float* __restrict__ fw2,
    int jsplit, int JW, long OM, long OJ, long OS, int SD) {
  __shared__ float2 Us[64][32];
  __shared__ float2 Wm[32][32];
  int m = blockIdx.x, j = blockIdx.y, t = threadIdx.x;
  int J = gridDim.y;
  const float2* U = Ub + (long)blockIdx.z * R3SLOT + (long)(m * J + j) * SD * 32;
  for (int k = t; k < SD * 32; k += 256) Us[k >> 5][k & 31] = U[k];
  {
    const float* src = (j < jsplit) ? fw : fw2;
    int jl = (j < jsplit) ? j : j - jsplit;
    for (int k = t; k < 1024; k += 256) {
      int i = k >> 5, o = k & 31;
      const float* p = src + (((i * 32 + o) * 16 + m) * JW + jl) * 2;
      Wm[i][o] = make_float2(p[0], p[1]);
    }
  }
  __syncthreads();
  int o = t & 31, sg = t >> 5;
  float2* V = Vb + (long)blockIdx.z * R2SLOT;
  for (int s = sg; s < SD; s += 8) {
    float2 acc = make_float2(0.f, 0.f);
    for (int i2 = 0; i2 < 32; ++i2) {
      float2 u = Us[s][i2], w = Wm[i2][o];
      acc.x += u.x * w.x - u.y * w.y;
      acc.y += u.x * w.y + u.y * w.x;
    }
    V[(long)m * OM + (long)j * OJ + (long)s * OS + o] = acc;
  }
}

// ---------------- inverse axis DFT (16 modes -> 64), unnormalized
__global__ __launch_bounds__(256) void k_invaxis(const float2* __restrict__ Vb,
    float2* __restrict__ Pb) {
  __shared__ float2 Vs[16][CID];
  __shared__ float2 twp[64];
  int s = blockIdx.x, j = blockIdx.y, t = threadIdx.x;
  const float2* V = Vb + (long)blockIdx.z * R2SLOT;
  float2* P = Pb + (long)blockIdx.z * R3SLOT;
  if (t < 64) {
    float s_, c_; sincosf(TWO_PI * t / 64.0f, &s_, &c_);
    twp[t] = make_float2(c_, s_);
  }
  for (int k = t; k < 512; k += 256) {
    int mm = k >> 5, o = k & 31;
    Vs[mm][o] = V[((long)(mm * 64 + s) * NJZ + j) * CID + o];
  }
  __syncthreads();
  int o = t & 31, vg = t >> 5;
  for (int k = 0; k < 8; ++k) {
    int v = vg + 8 * k;
    float2 acc = make_float2(0.f, 0.f);
    for (int mm = 0; mm < 16; ++mm) {
      float2 w = twp[(mm * v) & 63];
      float2 vv = Vs[mm][o];
      acc.x += vv.x * w.x - vv.y * w.y;
      acc.y += vv.x * w.y + vv.y * w.x;
    }
    P[((long)(v * 64 + s) * NJZ + j) * CID + o] = acc;
  }
}

// ---------------- inverse real-z (16 bins -> 40) + accumulate into out
__global__ __launch_bounds__(256) void k_invzadd(const float2* __restrict__ Pb,
    float* __restrict__ out, long strideV, long strideS, int b0) {
  __shared__ float2 czt[NJZ][NZD];
  int t = threadIdx.x;
  int b = b0 + blockIdx.z;
  const float2* P = Pb + (long)blockIdx.z * R3SLOT;
  for (int k = t; k < NJZ * NZD; k += 256) {
    int j = k / NZD, z = k % NZD;
    int kz = (j < 8) ? j : j + 5;
    int mm = (kz * z) % NZD;
    float s_, c_; sincosf(TWO_PI * mm / (float)NZD, &s_, &c_);
    float cj = (kz == 0 || kz == 20) ? 1.0f : 2.0f;
    cj *= (1.0f / 2560.0f);
    czt[j][z] = make_float2(cj * c_, cj * s_);
  }
  __syncthreads();
  int v = blockIdx.x;
  int s = blockIdx.y * 8 + (t >> 5);
  int o = t & 31;
  float2 pr[16];
  const float2* pp = P + ((long)(v * 64 + s) * NJZ) * CID + o;
  for (int j = 0; j < 16; ++j) pr[j] = pp[(long)j * CID];
  float* op = out + (long)b * NXD * NYD * NZD * CID + v * strideV + s * strideS + o;
  for (int z = 0; z < NZD; ++z) {
    float acc = 0.f;
    for (int j = 0; j < 16; ++j) {
      float2 c = czt[j][z];
      acc += pr[j].x * c.x - pr[j].y * c.y;
    }
    op[(long)z * CID] += acc;
  }
}

// ---------------- xy branch: forward real-y DFT (64 -> 32 bins)
__global__ __launch_bounds__(256) void k_fwdy(const float* __restrict__ X,
    float2* __restrict__ Sb, int b0) {
  __shared__ float xs[64][128];
  __shared__ float2 twy[NJY][64];
  int x = blockIdx.x, zc = blockIdx.y, t = threadIdx.x;
  int b = b0 + blockIdx.z;
  float2* S = Sb + (long)blockIdx.z * R1SLOT;
  int z0 = zc * 4;
  const float* base = X + (((long)b * 64 + x) * 64) * (long)NZD * CID;
  for (int k = t; k < 8192; k += 256) {
    int y = k >> 7, r = k & 127;
    int zt = r >> 5, i = r & 31;
    xs[y][r] = base[(long)y * (NZD * CID) + (z0 + zt) * CID + i];
  }
  for (int k = t; k < NJY * 64; k += 256) {
    int jy = k >> 6, y = k & 63;
    int ky = (jy < 16) ? jy : jy + 1;
    int mm = (ky * y) & 63;
    float s_, c_; sincosf(TWO_PI * mm / 64.0f, &s_, &c_);
    twy[jy][y] = make_float2(c_, -s_);
  }
  __syncthreads();
  int i = t & 31, g = t >> 5;
  for (int k2 = 0; k2 < 4; ++k2) {
    int jy = g * 4 + k2;
    for (int zt = 0; zt < 4; ++zt) {
      float2 acc = make_float2(0.f, 0.f);
      for (int y = 0; y < 64; ++y) {
        float v = xs[y][zt * 32 + i];
        float2 w = twy[jy][y];
        acc.x += v * w.x; acc.y += v * w.y;
      }
      S[(((long)x * NJY + jy) * NZD + z0 + zt) * CID + i] = acc;
    }
  }
}

// ---------------- xy branch: inverse x DFT (16 -> 64), unnormalized
__global__ __launch_bounds__(256) void k_invx_xy(const float2* __restrict__ V2b,
    float2* __restrict__ P2b) {
  __shared__ float2 Vs[16][CID];
  __shared__ float2 twp[64];
  int jy = blockIdx.x, z = blockIdx.y, t = threadIdx.x;
  const float2* V2 = V2b + (long)blockIdx.z * R2SLOT;
  float2* P2 = P2b + (long)blockIdx.z * R3SLOT;
  if (t < 64) {
    float s_, c_; sincosf(TWO_PI * t / 64.0f, &s_, &c_);
    twp[t] = make_float2(c_, s_);
  }
  for (int k = t; k < 512; k += 256) {
    int kx = k >> 5, o = k & 31;
    Vs[kx][o] = V2[(((long)kx * NJY + jy) * NZD + z) * CID + o];
  }
  __syncthreads();
  int o = t & 31, xg = t >> 5;
  for (int k = 0; k < 8; ++k) {
    int x = xg + 8 * k;
    float2 acc = make_float2(0.f, 0.f);
    for (int kx = 0; kx < 16; ++kx) {
      float2 w = twp[(kx * x) & 63];
      float2 v = Vs[kx][o];
      acc.x += v.x * w.x - v.y * w.y;
      acc.y += v.x * w.y + v.y * w.x;
    }
    P2[(((long)x * NJY + jy) * NZD + z) * CID + o] = acc;
  }
}

// ---------------- xy branch: inverse real-y (32 bins -> 64) + accumulate
__global__ __launch_bounds__(256) void k_invyadd(const float2* __restrict__ P2b,
    float* __restrict__ out, int b0) {
  __shared__ float2 cyt[NJY][64];
  int t = threadIdx.x;
  int b = b0 + blockIdx.z;
  const float2* P2 = P2b + (long)blockIdx.z * R3SLOT;
  for (int k = t; k < NJY * 64; k += 256) {
    int jy = k >> 6, y = k & 63;
    int ky = (jy < 16) ? jy : jy + 1;
    int mm = (ky * y) & 63;
    float s_, c_; sincosf(TWO_PI * mm / 64.0f, &s_, &c_);
    float cj = (ky == 0 || ky == 32) ? 1.0f : 2.0f;
    cj *= (1.0f / 4096.0f);
    cyt[jy][y] = make_float2(cj * c_, cj * s_);
  }
  __syncthreads();
  int x = blockIdx.x;
  int y0 = blockIdx.y * 8;
  int o = t & 31, zg = t >> 5;
  float* ob = out + (long)b * NXD * NYD * NZD * CID + (long)x * NYD * NZD * CID;
  for (int k = 0; k < 5; ++k) {
    int z = zg + 8 * k;
    float2 pr[NJY];
    const float2* pp = P2 + (((long)x * NJY) * NZD + z) * CID + o;
    for (int jy = 0; jy < NJY; ++jy) pr[jy] = pp[(long)jy * (NZD * CID)];
    for (int yy = 0; yy < 8; ++yy) {
      int y = y0 + yy;
      float acc = 0.f;
      for (int jy = 0; jy < NJY; ++jy) {
        float2 c = cyt[jy][y];
        acc += pr[jy].x * c.x - pr[jy].y * c.y;
      }
      ob[((long)y * NZD + z) * CID + o] += acc;
    }
  }
}

// ---------------- FFN via MFMA, in-place on out.
__global__ __launch_bounds__(256) void k_ff_mfma(float* __restrict__ out,
    const float* __restrict__ W0, const float* __restrict__ b0,
    const float* __restrict__ W1, const float* __restrict__ b1) {
  __shared__ unsigned short h1s[4][16 * 64];
  int t = threadIdx.x;
  int wid = t >> 6, lane = t & 63;
  int l15 = lane & 15, quad = lane >> 4;
  short8 B1[4];
  float bb0[4];
  for (int nt = 0; nt < 4; ++nt) {
    int hh = nt * 16 + l15;
    for (int j = 0; j < 8; ++j) B1[nt][j] = (short)f2bf(W0[hh * 32 + quad * 8 + j]);
    bb0[nt] = b0[hh];
  }
  short8 B2[2][2];
  float bb1[2];
  for (int k0 = 0; k0 < 2; ++k0)
    for (int nt = 0; nt < 2; ++nt) {
      int o = nt * 16 + l15;
      for (int j = 0; j < 8; ++j)
        B2[k0][nt][j] = (short)f2bf(W1[o * 64 + k0 * 32 + quad * 8 + j]);
    }
  for (int nt = 0; nt < 2; ++nt) bb1[nt] = b1[nt * 16 + l15];

  const int TOT = 40960;
  int wg = blockIdx.x * 4 + wid;
  unsigned short* hs = h1s[wid];
  for (int tt = wg; tt < TOT; tt += gridDim.x * 4) {
    long r0 = (long)tt * 16;
    const float4v* p = (const float4v*)(out + (r0 + l15) * 32 + quad * 8);
    float4v x0 = p[0], x1 = p[1];
    short8 a1;
    for (int j = 0; j < 4; ++j) { a1[j] = (short)f2bf(x0[j]); a1[4 + j] = (short)f2bf(x1[j]); }
    for (int nt = 0; nt < 4; ++nt) {
      float4v acc = {0.f, 0.f, 0.f, 0.f};
      acc = __builtin_amdgcn_mfma_f32_16x16x32_bf16(a1, B1[nt], acc, 0, 0, 0);
      for (int r = 0; r < 4; ++r) {
        float v = acc[r] + bb0[nt];
        v = v > 0.f ? v : 0.f;
        hs[(quad * 4 + r) * 64 + nt * 16 + l15] = f2bf(v);
      }
    }
    short8 a2[2];
    for (int k0 = 0; k0 < 2; ++k0)
      a2[k0] = *(const short8*)&hs[l15 * 64 + k0 * 32 + quad * 8];
    for (int nt = 0; nt < 2; ++nt) {
      float4v acc = {0.f, 0.f, 0.f, 0.f};
      acc = __builtin_amdgcn_mfma_f32_16x16x32_bf16(a2[0], B2[0][nt], acc, 0, 0, 0);
      acc = __builtin_amdgcn_mfma_f32_16x16x32_bf16(a2[1], B2[1][nt], acc, 0, 0, 0);
      for (int r = 0; r < 4; ++r)
        out[(r0 + quad * 4 + r) * 32 + nt * 16 + l15] = acc[r] + bb1[nt];
    }
  }
}

extern "C" void kernel_launch(void* const* d_in, const int* in_sizes, int n_in,
                              void* d_out, int out_size, void* d_ws, size_t ws_size,
                              hipStream_t stream) {
  const float* X       = (const float*)d_in[0];
  const float* w_w     = (const float*)d_in[1];
  const float* w_b     = (const float*)d_in[2];
  const float* fw_xy   = (const float*)d_in[3];
  const float* fw_yz   = (const float*)d_in[4];
  const float* fw_xz   = (const float*)d_in[5];
  const float* fw2_xy  = (const float*)d_in[6];
  const float* fw2_yz  = (const float*)d_in[7];
  const float* fw2_xz  = (const float*)d_in[8];
  const float* ff_w0   = (const float*)d_in[9];
  const float* ff_b0   = (const float*)d_in[10];
  const float* ff_w1   = (const float*)d_in[11];
  const float* ff_b1   = (const float*)d_in[12];
  float* out = (float*)d_out;
  char* ws = (char*)d_ws;

  const size_t need_full = (size_t)(R1SLOT + R2SLOT + R3SLOT) * 4 * 8;
  bool full = ws_size >= need_full;

  float2 *r1, *r2, *r3;
  if (full) {
    r1 = (float2*)ws;
    r2 = (float2*)(ws + (size_t)R1SLOT * 4 * 8);
    r3 = (float2*)(ws + (size_t)(R1SLOT + R2SLOT) * 4 * 8);
  } else {
    r1 = (float2*)ws;
    r2 = (float2*)(ws + (size_t)R1SLOT * 8);
    r3 = (float2*)(ws + (size_t)(R1SLOT + R2SLOT) * 8);
  }

  k_conv_mfma<<<dim3(2560), dim3(256), 0, stream>>>(X, w_w, w_b, out);

  int nz = full ? 4 : 1;
  int nb = full ? 1 : 4;
  for (int b = 0; b < nb; ++b) {
    // shared z-projection for xz & yz (T in r1)
    k_zproj<<<dim3(4096, 1, nz), dim3(512), 0, stream>>>(X, r1, b);
    // ---- xz branch: contract x. T idx: x*32768 + y*512 + j*32 + i
    k_fwddft<<<dim3(16, 8, nz), dim3(256), 0, stream>>>(r1, r3, 32768, 512, 32);
    k_mix<<<dim3(16, 16, nz), dim3(256), 0, stream>>>(r3, r2, fw_xz, fw2_xz,
        8, 8, 32768, 32, 512, 64);
    k_invaxis<<<dim3(64, 16, nz), dim3(256), 0, stream>>>(r2, r3);
    k_invzadd<<<dim3(64, 8, nz), dim3(256), 0, stream>>>(r3, out, 64 * 40 * 32, 40 * 32, b);
    // ---- yz branch: contract y. T idx: y*512 + x*32768 + j*32 + i
    k_fwddft<<<dim3(16, 8, nz), dim3(256), 0, stream>>>(r1, r3, 512, 32768, 32);
    k_mix<<<dim3(16, 16, nz), dim3(256), 0, stream>>>(r3, r2, fw_yz, fw2_yz,
        8, 8, 32768, 32, 512, 64);
    k_invaxis<<<dim3(64, 16, nz), dim3(256), 0, stream>>>(r2, r3);
    k_invzadd<<<dim3(64, 8, nz), dim3(256), 0, stream>>>(r3, out, 40 * 32, 64 * 40 * 32, b);
    // ---- xy branch (S in r1): S idx: x*40960 + jy*1280 + z*32 + i
    k_fwdy<<<dim3(64, 10, nz), dim3(256), 0, stream>>>(X, r1, b);
    k_fwddft<<<dim3(32, 5, nz), dim3(256), 0, stream>>>(r1, r3, 40960, 32, 1280);
    k_mix<<<dim3(16, 32, nz), dim3(256), 0, stream>>>(r3, r2, fw_xy, fw2_xy,
        16, 16, 40960, 1280, 32, 40);
    k_invx_xy<<<dim3(32, 40, nz), dim3(256), 0, stream>>>(r2, r3);
    k_invyadd<<<dim3(64, 8, nz), dim3(256), 0, stream>>>(r3, out, b);
  }

  k_ff_mfma<<<dim3(2560), dim3(256), 0, stream>>>(out, ff_w0, ff_b0, ff_w1, ff_b1);
}

// Round 4
// 1050.649 us; speedup vs baseline: 2.5949x; 1.2286x over previous
//
#include <hip/hip_runtime.h>
#include <math.h>

#define TWO_PI 6.28318530717958647692f
#define NXD 64
#define NYD 64
#define NZD 40
#define CID 32
#define NJZ 16   // kept z bins: kz = 0..7, 13..20
#define NJY 32   // kept y bins (xy branch): ky = 0..15, 17..32

// workspace slot strides (float2 elements per batch-slot)
#define R1SLOT 2621440ll   // max(T=2097152, S=2621440)
#define R2SLOT 655360ll    // max(V=524288, V2=655360)
#define R3SLOT 2621440ll   // max(P=2097152, P2=2621440, U=655360)

typedef __attribute__((ext_vector_type(8))) short short8;
typedef __attribute__((ext_vector_type(4))) float float4v;

__device__ inline unsigned short f2bf(float f) {
  unsigned u = __builtin_bit_cast(unsigned, f);
  unsigned r = (u + 0x7fffu + ((u >> 16) & 1u)) >> 16;
  return (unsigned short)r;
}

// ---------------- 1x1 conv via MFMA
__global__ __launch_bounds__(256) void k_conv_mfma(const float* __restrict__ X,
    const float* __restrict__ Wc, const float* __restrict__ bias,
    float* __restrict__ out) {
  int t = threadIdx.x;
  int wid = t >> 6, lane = t & 63;
  int l15 = lane & 15, quad = lane >> 4;
  short8 B[2];
  float bb[2];
  for (int nt = 0; nt < 2; ++nt) {
    int o = nt * 16 + l15;
    for (int j = 0; j < 8; ++j) B[nt][j] = (short)f2bf(Wc[o * 32 + quad * 8 + j]);
    bb[nt] = bias[o];
  }
  const int TOT = 40960;
  int wg = blockIdx.x * 4 + wid;
  for (int tt = wg; tt < TOT; tt += gridDim.x * 4) {
    long r0 = (long)tt * 16;
    const float4v* p = (const float4v*)(X + (r0 + l15) * 32 + quad * 8);
    float4v x0 = p[0], x1 = p[1];
    short8 a;
    for (int j = 0; j < 4; ++j) { a[j] = (short)f2bf(x0[j]); a[4 + j] = (short)f2bf(x1[j]); }
    for (int nt = 0; nt < 2; ++nt) {
      float4v acc = {0.f, 0.f, 0.f, 0.f};
      acc = __builtin_amdgcn_mfma_f32_16x16x32_bf16(a, B[nt], acc, 0, 0, 0);
      for (int r = 0; r < 4; ++r)
        out[(r0 + quad * 4 + r) * 32 + nt * 16 + l15] = acc[r] + bb[nt];
    }
  }
}

// ---------------- z projection (shared by xz & yz branches)
__global__ __launch_bounds__(512) void k_zproj(const float* __restrict__ X,
    float2* __restrict__ Tb, int b0) {
  __shared__ float xs[NZD][CID];
  __shared__ float2 tw[NJZ][NZD];
  int t = threadIdx.x;
  int xy = blockIdx.x;
  int b = b0 + blockIdx.z;
  float2* T = Tb + (long)blockIdx.z * R1SLOT;
  const float* src = X + ((long)(b * 4096 + xy)) * NZD * CID;
  for (int k = t; k < NZD * CID; k += 512) xs[k >> 5][k & 31] = src[k];
  for (int k = t; k < NJZ * NZD; k += 512) {
    int j = k / NZD, z = k % NZD;
    int kz = (j < 8) ? j : j + 5;
    int m = (kz * z) % NZD;
    float s_, c_; sincosf(TWO_PI * m / (float)NZD, &s_, &c_);
    tw[j][z] = make_float2(c_, -s_);
  }
  __syncthreads();
  int j = t >> 5, i = t & 31;
  float2 acc = make_float2(0.f, 0.f);
  for (int z = 0; z < NZD; ++z) {
    float v = xs[z][i];
    float2 w = tw[j][z];
    acc.x += v * w.x; acc.y += v * w.y;
  }
  T[((long)xy * NJZ + j) * CID + i] = acc;
}

// ---------------- streaming forward-axis DFT (64 -> 16 modes), amplification-free.
__global__ __launch_bounds__(256) void k_fwddft(const float2* __restrict__ inb,
    float2* __restrict__ Ub, long CS, long SS, long JS) {
  __shared__ float2 tw[64];
  int t = threadIdx.x;
  if (t < 64) {
    float s_, c_; sincosf(TWO_PI * t / 64.0f, &s_, &c_);
    tw[t] = make_float2(c_, -s_);
  }
  int j = blockIdx.x, sc = blockIdx.y;
  int J = gridDim.x, SD = gridDim.y * 8;
  int s = sc * 8 + (t >> 5), i = t & 31;
  const float2* in = inb + (long)blockIdx.z * R1SLOT + (long)j * JS + (long)s * SS + i;
  float2 acc[16];
#pragma unroll
  for (int m = 0; m < 16; ++m) acc[m] = make_float2(0.f, 0.f);
  __syncthreads();
  for (int c = 0; c < 64; ++c) {
    float2 v = in[(long)c * CS];
#pragma unroll
    for (int m = 0; m < 16; ++m) {
      float2 w = tw[(m * c) & 63];
      acc[m].x += v.x * w.x - v.y * w.y;
      acc[m].y += v.x * w.y + v.y * w.x;
    }
  }
  float2* U = Ub + (long)blockIdx.z * R3SLOT;
#pragma unroll
  for (int m = 0; m < 16; ++m)
    U[((long)(m * J + j) * SD + s) * 32 + i] = acc[m];
}

// ---------------- unified channel mode-mix: V[m,j,s,o] = sum_i U[m,j,s,i]*W[m,j][i][o]
__global__ __launch_bounds__(256) void k_mix(const float2* __restrict__ Ub,
    float2* __restrict__ Vb, const float* __restrict__ fw, const float* __restrict__ fw2,
    int jsplit, int JW, long OM, long OJ, long OS, int SD) {
  __shared__ float2 Us[64][32];
  __shared__ float2 Wm[32][32];
  int m = blockIdx.x, j = blockIdx.y, t = threadIdx.x;
  int J = gridDim.y;
  const float2* U = Ub + (long)blockIdx.z * R3SLOT + (long)(m * J + j) * SD * 32;
  for (int k = t; k < SD * 32; k += 256) Us[k >> 5][k & 31] = U[k];
  {
    const float* src = (j < jsplit) ? fw : fw2;
    int jl = (j < jsplit) ? j : j - jsplit;
    for (int k = t; k < 1024; k += 256) {
      int i = k >> 5, o = k & 31;
      const float* p = src + (((i * 32 + o) * 16 + m) * JW + jl) * 2;
      Wm[i][o] = make_float2(p[0], p[1]);
    }
  }
  __syncthreads();
  int o = t & 31, sg = t >> 5;
  float2* V = Vb + (long)blockIdx.z * R2SLOT;
  for (int s = sg; s < SD; s += 8) {
    float2 acc = make_float2(0.f, 0.f);
    for (int i2 = 0; i2 < 32; ++i2) {
      float2 u = Us[s][i2], w = Wm[i2][o];
      acc.x += u.x * w.x - u.y * w.y;
      acc.y += u.x * w.y + u.y * w.x;
    }
    V[(long)m * OM + (long)j * OJ + (long)s * OS + o] = acc;
  }
}

// ---------------- inverse axis DFT (16 modes -> 64), unnormalized
__global__ __launch_bounds__(256) void k_invaxis(const float2* __restrict__ Vb,
    float2* __restrict__ Pb) {
  __shared__ float2 Vs[16][CID];
  __shared__ float2 twp[64];
  int s = blockIdx.x, j = blockIdx.y, t = threadIdx.x;
  const float2* V = Vb + (long)blockIdx.z * R2SLOT;
  float2* P = Pb + (long)blockIdx.z * R3SLOT;
  if (t < 64) {
    float s_, c_; sincosf(TWO_PI * t / 64.0f, &s_, &c_);
    twp[t] = make_float2(c_, s_);
  }
  for (int k = t; k < 512; k += 256) {
    int mm = k >> 5, o = k & 31;
    Vs[mm][o] = V[((long)(mm * 64 + s) * NJZ + j) * CID + o];
  }
  __syncthreads();
  int o = t & 31, vg = t >> 5;
  for (int k = 0; k < 8; ++k) {
    int v = vg + 8 * k;
    float2 acc = make_float2(0.f, 0.f);
    for (int mm = 0; mm < 16; ++mm) {
      float2 w = twp[(mm * v) & 63];
      float2 vv = Vs[mm][o];
      acc.x += vv.x * w.x - vv.y * w.y;
      acc.y += vv.x * w.y + vv.y * w.x;
    }
    P[((long)(v * 64 + s) * NJZ + j) * CID + o] = acc;
  }
}

// ---------------- inverse real-z (16 bins -> 40) + accumulate into out
__global__ __launch_bounds__(256) void k_invzadd(const float2* __restrict__ Pb,
    float* __restrict__ out, long strideV, long strideS, int b0) {
  __shared__ float2 czt[NJZ][NZD];
  int t = threadIdx.x;
  int b = b0 + blockIdx.z;
  const float2* P = Pb + (long)blockIdx.z * R3SLOT;
  for (int k = t; k < NJZ * NZD; k += 256) {
    int j = k / NZD, z = k % NZD;
    int kz = (j < 8) ? j : j + 5;
    int mm = (kz * z) % NZD;
    float s_, c_; sincosf(TWO_PI * mm / (float)NZD, &s_, &c_);
    float cj = (kz == 0 || kz == 20) ? 1.0f : 2.0f;
    cj *= (1.0f / 2560.0f);
    czt[j][z] = make_float2(cj * c_, cj * s_);
  }
  __syncthreads();
  int v = blockIdx.x;
  int s = blockIdx.y * 8 + (t >> 5);
  int o = t & 31;
  float2 pr[16];
  const float2* pp = P + ((long)(v * 64 + s) * NJZ) * CID + o;
  for (int j = 0; j < 16; ++j) pr[j] = pp[(long)j * CID];
  float* op = out + (long)b * NXD * NYD * NZD * CID + v * strideV + s * strideS + o;
  for (int z = 0; z < NZD; ++z) {
    float acc = 0.f;
    for (int j = 0; j < 16; ++j) {
      float2 c = czt[j][z];
      acc += pr[j].x * c.x - pr[j].y * c.y;
    }
    op[(long)z * CID] += acc;
  }
}

// ---------------- xy branch: forward real-y DFT via MFMA (64 -> 32 bins)
// S[x,jy,z,i] = sum_y X[b,x,y,z,i] * e^{-2pi i ky(jy) y/64}
// GEMM per (b,x): M=1280 (m=z*32+i), K=64 (y), N=64 (n=jy*2+part)
// grid (5 m-chunks, 64 x, nz). block 256 = 4 waves; wave owns 64 rows.
__global__ __launch_bounds__(256) void k_fwdy_mfma(const float* __restrict__ X,
    float2* __restrict__ Sb, int b0) {
  __shared__ unsigned short Xs[256][72];  // [m][y] bf16, pad 72: frag reads 2-way (free)
  __shared__ float2 twtab[64];            // (cos, sin) of 2*pi*a/64
  int t = threadIdx.x;
  int wid = t >> 6, lane = t & 63;
  int l15 = lane & 15, quad = lane >> 4;
  int b = b0 + blockIdx.z;
  int x = blockIdx.y;
  int m0 = blockIdx.x * 256;
  if (t < 64) {
    float s_, c_; sincosf(TWO_PI * t / 64.0f, &s_, &c_);
    twtab[t] = make_float2(c_, s_);
  }
  __syncthreads();
  // B fragments: n = nt*16+l15 -> jy=n>>1, part=n&1 ; k = kt*32+quad*8+j -> y
  // value = part ? -sin(2pi ky y/64) : cos(2pi ky y/64)
  short8 Bf[2][4];
  for (int nt = 0; nt < 4; ++nt) {
    int n = nt * 16 + l15;
    int jy = n >> 1, part = n & 1;
    int ky = (jy < 16) ? jy : jy + 1;
    for (int kt = 0; kt < 2; ++kt)
      for (int j = 0; j < 8; ++j) {
        int y = kt * 32 + quad * 8 + j;
        float2 w = twtab[(ky * y) & 63];
        Bf[kt][nt][j] = (short)f2bf(part ? -w.y : w.x);
      }
  }
  // stage X[b,x,y, m0..m0+255] -> Xs[m][y] (transposed, bf16)
  const float* src = X + (((long)b * 64 + x) * 64) * 1280 + m0;
  for (int k = t; k < 64 * 256; k += 256) {
    int y = k >> 8, m = k & 255;
    Xs[m][y] = f2bf(src[(long)y * 1280 + m]);
  }
  __syncthreads();
  float2* S = Sb + (long)blockIdx.z * R1SLOT + (long)x * (NJY * NZD * CID);
  for (int mt = 0; mt < 4; ++mt) {
    int mrow = wid * 64 + mt * 16 + l15;
    short8 a0 = *(const short8*)&Xs[mrow][quad * 8];
    short8 a1 = *(const short8*)&Xs[mrow][32 + quad * 8];
    for (int nt = 0; nt < 4; ++nt) {
      float4v acc = {0.f, 0.f, 0.f, 0.f};
      acc = __builtin_amdgcn_mfma_f32_16x16x32_bf16(a0, Bf[0][nt], acc, 0, 0, 0);
      acc = __builtin_amdgcn_mfma_f32_16x16x32_bf16(a1, Bf[1][nt], acc, 0, 0, 0);
      int n = nt * 16 + l15, jy = n >> 1, part = n & 1;
      for (int r = 0; r < 4; ++r) {
        int m = m0 + wid * 64 + mt * 16 + quad * 4 + r;
        int z = m >> 5, i = m & 31;
        ((float*)&S[((long)jy * NZD + z) * CID + i])[part] = acc[r];
      }
    }
  }
}

// ---------------- xy branch: inverse x DFT (16 -> 64), unnormalized
__global__ __launch_bounds__(256) void k_invx_xy(const float2* __restrict__ V2b,
    float2* __restrict__ P2b) {
  __shared__ float2 Vs[16][CID];
  __shared__ float2 twp[64];
  int jy = blockIdx.x, z = blockIdx.y, t = threadIdx.x;
  const float2* V2 = V2b + (long)blockIdx.z * R2SLOT;
  float2* P2 = P2b + (long)blockIdx.z * R3SLOT;
  if (t < 64) {
    float s_, c_; sincosf(TWO_PI * t / 64.0f, &s_, &c_);
    twp[t] = make_float2(c_, s_);
  }
  for (int k = t; k < 512; k += 256) {
    int kx = k >> 5, o = k & 31;
    Vs[kx][o] = V2[(((long)kx * NJY + jy) * NZD + z) * CID + o];
  }
  __syncthreads();
  int o = t & 31, xg = t >> 5;
  for (int k = 0; k < 8; ++k) {
    int x = xg + 8 * k;
    float2 acc = make_float2(0.f, 0.f);
    for (int kx = 0; kx < 16; ++kx) {
      float2 w = twp[(kx * x) & 63];
      float2 v = Vs[kx][o];
      acc.x += v.x * w.x - v.y * w.y;
      acc.y += v.x * w.y + v.y * w.x;
    }
    P2[(((long)x * NJY + jy) * NZD + z) * CID + o] = acc;
  }
}

// ---------------- xy branch: inverse real-y (32 bins -> 64) + accumulate
__global__ __launch_bounds__(256) void k_invyadd(const float2* __restrict__ P2b,
    float* __restrict__ out, int b0) {
  __shared__ float2 cyt[NJY][64];
  int t = threadIdx.x;
  int b = b0 + blockIdx.z;
  const float2* P2 = P2b + (long)blockIdx.z * R3SLOT;
  for (int k = t; k < NJY * 64; k += 256) {
    int jy = k >> 6, y = k & 63;
    int ky = (jy < 16) ? jy : jy + 1;
    int mm = (ky * y) & 63;
    float s_, c_; sincosf(TWO_PI * mm / 64.0f, &s_, &c_);
    float cj = (ky == 0 || ky == 32) ? 1.0f : 2.0f;
    cj *= (1.0f / 4096.0f);
    cyt[jy][y] = make_float2(cj * c_, cj * s_);
  }
  __syncthreads();
  int x = blockIdx.x;
  int y0 = blockIdx.y * 8;
  int o = t & 31, zg = t >> 5;
  float* ob = out + (long)b * NXD * NYD * NZD * CID + (long)x * NYD * NZD * CID;
  for (int k = 0; k < 5; ++k) {
    int z = zg + 8 * k;
    float2 pr[NJY];
    const float2* pp = P2 + (((long)x * NJY) * NZD + z) * CID + o;
    for (int jy = 0; jy < NJY; ++jy) pr[jy] = pp[(long)jy * (NZD * CID)];
    for (int yy = 0; yy < 8; ++yy) {
      int y = y0 + yy;
      float acc = 0.f;
      for (int jy = 0; jy < NJY; ++jy) {
        float2 c = cyt[jy][y];
        acc += pr[jy].x * c.x - pr[jy].y * c.y;
      }
      ob[((long)y * NZD + z) * CID + o] += acc;
    }
  }
}

// ---------------- FFN via MFMA, in-place on out.
__global__ __launch_bounds__(256) void k_ff_mfma(float* __restrict__ out,
    const float* __restrict__ W0, const float* __restrict__ b0,
    const float* __restrict__ W1, const float* __restrict__ b1) {
  __shared__ unsigned short h1s[4][16 * 64];
  int t = threadIdx.x;
  int wid = t >> 6, lane = t & 63;
  int l15 = lane & 15, quad = lane >> 4;
  short8 B1[4];
  float bb0[4];
  for (int nt = 0; nt < 4; ++nt) {
    int hh = nt * 16 + l15;
    for (int j = 0; j < 8; ++j) B1[nt][j] = (short)f2bf(W0[hh * 32 + quad * 8 + j]);
    bb0[nt] = b0[hh];
  }
  short8 B2[2][2];
  float bb1[2];
  for (int k0 = 0; k0 < 2; ++k0)
    for (int nt = 0; nt < 2; ++nt) {
      int o = nt * 16 + l15;
      for (int j = 0; j < 8; ++j)
        B2[k0][nt][j] = (short)f2bf(W1[o * 64 + k0 * 32 + quad * 8 + j]);
    }
  for (int nt = 0; nt < 2; ++nt) bb1[nt] = b1[nt * 16 + l15];

  const int TOT = 40960;
  int wg = blockIdx.x * 4 + wid;
  unsigned short* hs = h1s[wid];
  for (int tt = wg; tt < TOT; tt += gridDim.x * 4) {
    long r0 = (long)tt * 16;
    const float4v* p = (const float4v*)(out + (r0 + l15) * 32 + quad * 8);
    float4v x0 = p[0], x1 = p[1];
    short8 a1;
    for (int j = 0; j < 4; ++j) { a1[j] = (short)f2bf(x0[j]); a1[4 + j] = (short)f2bf(x1[j]); }
    for (int nt = 0; nt < 4; ++nt) {
      float4v acc = {0.f, 0.f, 0.f, 0.f};
      acc = __builtin_amdgcn_mfma_f32_16x16x32_bf16(a1, B1[nt], acc, 0, 0, 0);
      for (int r = 0; r < 4; ++r) {
        float v = acc[r] + bb0[nt];
        v = v > 0.f ? v : 0.f;
        hs[(quad * 4 + r) * 64 + nt * 16 + l15] = f2bf(v);
      }
    }
    short8 a2[2];
    for (int k0 = 0; k0 < 2; ++k0)
      a2[k0] = *(const short8*)&hs[l15 * 64 + k0 * 32 + quad * 8];
    for (int nt = 0; nt < 2; ++nt) {
      float4v acc = {0.f, 0.f, 0.f, 0.f};
      acc = __builtin_amdgcn_mfma_f32_16x16x32_bf16(a2[0], B2[0][nt], acc, 0, 0, 0);
      acc = __builtin_amdgcn_mfma_f32_16x16x32_bf16(a2[1], B2[1][nt], acc, 0, 0, 0);
      for (int r = 0; r < 4; ++r)
        out[(r0 + quad * 4 + r) * 32 + nt * 16 + l15] = acc[r] + bb1[nt];
    }
  }
}

extern "C" void kernel_launch(void* const* d_in, const int* in_sizes, int n_in,
                              void* d_out, int out_size, void* d_ws, size_t ws_size,
                              hipStream_t stream) {
  const float* X       = (const float*)d_in[0];
  const float* w_w     = (const float*)d_in[1];
  const float* w_b     = (const float*)d_in[2];
  const float* fw_xy   = (const float*)d_in[3];
  const float* fw_yz   = (const float*)d_in[4];
  const float* fw_xz   = (const float*)d_in[5];
  const float* fw2_xy  = (const float*)d_in[6];
  const float* fw2_yz  = (const float*)d_in[7];
  const float* fw2_xz  = (const float*)d_in[8];
  const float* ff_w0   = (const float*)d_in[9];
  const float* ff_b0   = (const float*)d_in[10];
  const float* ff_w1   = (const float*)d_in[11];
  const float* ff_b1   = (const float*)d_in[12];
  float* out = (float*)d_out;
  char* ws = (char*)d_ws;

  const size_t need_full = (size_t)(R1SLOT + R2SLOT + R3SLOT) * 4 * 8;
  bool full = ws_size >= need_full;

  float2 *r1, *r2, *r3;
  if (full) {
    r1 = (float2*)ws;
    r2 = (float2*)(ws + (size_t)R1SLOT * 4 * 8);
    r3 = (float2*)(ws + (size_t)(R1SLOT + R2SLOT) * 4 * 8);
  } else {
    r1 = (float2*)ws;
    r2 = (float2*)(ws + (size_t)R1SLOT * 8);
    r3 = (float2*)(ws + (size_t)(R1SLOT + R2SLOT) * 8);
  }

  k_conv_mfma<<<dim3(2560), dim3(256), 0, stream>>>(X, w_w, w_b, out);

  int nz = full ? 4 : 1;
  int nb = full ? 1 : 4;
  for (int b = 0; b < nb; ++b) {
    // shared z-projection for xz & yz (T in r1)
    k_zproj<<<dim3(4096, 1, nz), dim3(512), 0, stream>>>(X, r1, b);
    // ---- xz branch: contract x. T idx: x*32768 + y*512 + j*32 + i
    k_fwddft<<<dim3(16, 8, nz), dim3(256), 0, stream>>>(r1, r3, 32768, 512, 32);
    k_mix<<<dim3(16, 16, nz), dim3(256), 0, stream>>>(r3, r2, fw_xz, fw2_xz,
        8, 8, 32768, 32, 512, 64);
    k_invaxis<<<dim3(64, 16, nz), dim3(256), 0, stream>>>(r2, r3);
    k_invzadd<<<dim3(64, 8, nz), dim3(256), 0, stream>>>(r3, out, 64 * 40 * 32, 40 * 32, b);
    // ---- yz branch: contract y. T idx: y*512 + x*32768 + j*32 + i
    k_fwddft<<<dim3(16, 8, nz), dim3(256), 0, stream>>>(r1, r3, 512, 32768, 32);
    k_mix<<<dim3(16, 16, nz), dim3(256), 0, stream>>>(r3, r2, fw_yz, fw2_yz,
        8, 8, 32768, 32, 512, 64);
    k_invaxis<<<dim3(64, 16, nz), dim3(256), 0, stream>>>(r2, r3);
    k_invzadd<<<dim3(64, 8, nz), dim3(256), 0, stream>>>(r3, out, 40 * 32, 64 * 40 * 32, b);
    // ---- xy branch (S in r1): S idx: x*40960 + jy*1280 + z*32 + i
    k_fwdy_mfma<<<dim3(5, 64, nz), dim3(256), 0, stream>>>(X, r1, b);
    k_fwddft<<<dim3(32, 5, nz), dim3(256), 0, stream>>>(r1, r3, 40960, 32, 1280);
    k_mix<<<dim3(16, 32, nz), dim3(256), 0, stream>>>(r3, r2, fw_xy, fw2_xy,
        16, 16, 40960, 1280, 32, 40);
    k_invx_xy<<<dim3(32, 40, nz), dim3(256), 0, stream>>>(r2, r3);
    k_invyadd<<<dim3(64, 8, nz), dim3(256), 0, stream>>>(r3, out, b);
  }

  k_ff_mfma<<<dim3(2560), dim3(256), 0, stream>>>(out, ff_w0, ff_b0, ff_w1, ff_b1);
}